// Round 1
// baseline (354.726 us; speedup 1.0000x reference)
//
#include <hip/hip_runtime.h>
#include <hip/hip_bf16.h>
#include <math.h>

#define NEG_SLOPE 0.2f

__device__ __forceinline__ float lrelu(float v) {
    return v > 0.0f ? v : NEG_SLOPE * v;
}

__device__ __forceinline__ float wred_max(float v) {
    #pragma unroll
    for (int d = 32; d; d >>= 1) v = fmaxf(v, __shfl_xor(v, d));
    return v;
}

__device__ __forceinline__ float wred_sum(float v) {
    #pragma unroll
    for (int d = 32; d; d >>= 1) v += __shfl_xor(v, d);
    return v;
}

__global__ void k_zero(int* p, int n) {
    int i = blockIdx.x * blockDim.x + threadIdx.x;
    if (i < n) p[i] = 0;
}

__global__ void k_hist(const int* __restrict__ dst, int E, int* __restrict__ counts) {
    int i = blockIdx.x * blockDim.x + threadIdx.x;
    if (i < E) atomicAdd(&counts[dst[i]], 1);
}

// Single-block exclusive scan over n counts -> offsets[0..n], cursor copy.
__global__ __launch_bounds__(1024) void k_scan(const int* __restrict__ counts,
                                               int* __restrict__ offsets,
                                               int* __restrict__ cursor, int n) {
    __shared__ int wsums[16];
    __shared__ int carry_sh;
    int tid = threadIdx.x;
    int lane = tid & 63;
    int wv = tid >> 6;
    if (tid == 0) carry_sh = 0;
    __syncthreads();
    for (int base = 0; base < n; base += 1024) {
        int i = base + tid;
        int v = (i < n) ? counts[i] : 0;
        int x = v;
        #pragma unroll
        for (int d = 1; d < 64; d <<= 1) {
            int y = __shfl_up(x, d);
            if (lane >= d) x += y;
        }
        if (lane == 63) wsums[wv] = x;
        __syncthreads();
        if (wv == 0) {
            int s = (lane < 16) ? wsums[lane] : 0;
            #pragma unroll
            for (int d = 1; d < 16; d <<= 1) {
                int y = __shfl_up(s, d);
                if (lane >= d) s += y;
            }
            if (lane < 16) wsums[lane] = s;
        }
        __syncthreads();
        int excl = carry_sh + (wv > 0 ? wsums[wv - 1] : 0) + (x - v);
        if (i < n) { offsets[i] = excl; cursor[i] = excl; }
        __syncthreads();
        if (tid == 0) carry_sh += wsums[15];
        __syncthreads();
    }
    if (tid == 0) offsets[n] = carry_sh;
}

__global__ void k_scatter(const int* __restrict__ src, const int* __restrict__ dst,
                          int E, int* __restrict__ cursor, int* __restrict__ csr_src) {
    int i = blockIdx.x * blockDim.x + threadIdx.x;
    if (i < E) {
        int d = dst[i];
        int pos = atomicAdd(&cursor[d], 1);
        csr_src[pos] = src[i];
    }
}

// XL[n,128] = X[n,128] @ W[128,128], f32. Block: 256 thr, 32 rows x 128 cols,
// 4x4 register blocking. W staged in LDS in two 64-row halves (48KB total LDS).
__global__ __launch_bounds__(256) void k_gemm(const float* __restrict__ X,
                                              const float* __restrict__ W,
                                              float* __restrict__ XL, int n) {
    __shared__ float Wl[64 * 128];  // 32KB
    __shared__ float Xl[32 * 128];  // 16KB
    int tid = threadIdx.x;
    int row0 = blockIdx.x * 32;
    {
        const float4* X4 = (const float4*)X;
        float4* Xl4 = (float4*)Xl;
        for (int i = tid; i < 32 * 32; i += 256) {
            int r = i >> 5;
            int gr = row0 + r;
            Xl4[i] = (gr < n) ? X4[(size_t)gr * 32 + (i & 31)] : make_float4(0, 0, 0, 0);
        }
    }
    int tc = tid & 31, tr = tid >> 5;
    float acc[4][4] = {};
    for (int kb = 0; kb < 128; kb += 64) {
        __syncthreads();
        const float4* W4 = (const float4*)(W + (size_t)kb * 128);
        float4* Wl4 = (float4*)Wl;
        for (int i = tid; i < 2048; i += 256) Wl4[i] = W4[i];
        __syncthreads();
        #pragma unroll 8
        for (int kk = 0; kk < 64; ++kk) {
            int k = kb + kk;
            float4 wv = *(const float4*)&Wl[kk * 128 + tc * 4];
            float xv[4];
            #pragma unroll
            for (int i = 0; i < 4; i++) xv[i] = Xl[(tr * 4 + i) * 128 + k];
            #pragma unroll
            for (int i = 0; i < 4; i++) {
                acc[i][0] += xv[i] * wv.x;
                acc[i][1] += xv[i] * wv.y;
                acc[i][2] += xv[i] * wv.z;
                acc[i][3] += xv[i] * wv.w;
            }
        }
    }
    #pragma unroll
    for (int i = 0; i < 4; i++) {
        int r = row0 + tr * 4 + i;
        if (r < n)
            *(float4*)&XL[(size_t)r * 128 + tc * 4] =
                make_float4(acc[i][0], acc[i][1], acc[i][2], acc[i][3]);
    }
}

// a_s[n] = dot(xl[n,:], att_src), a_d[n] = dot(xl[n,:], att_dst). One wave/node.
__global__ __launch_bounds__(256) void k_attn(const float* __restrict__ xl,
                                              const float* __restrict__ att_s,
                                              const float* __restrict__ att_d,
                                              float* __restrict__ a_s,
                                              float* __restrict__ a_d, int n) {
    int wid = (blockIdx.x * blockDim.x + threadIdx.x) >> 6;
    int lane = threadIdx.x & 63;
    if (wid >= n) return;
    float2 v = ((const float2*)xl)[(size_t)wid * 64 + lane];
    float2 s2 = ((const float2*)att_s)[lane];
    float2 d2 = ((const float2*)att_d)[lane];
    float ps = v.x * s2.x + v.y * s2.y;
    float pd = v.x * d2.x + v.y * d2.y;
    ps = wred_sum(ps);
    pd = wred_sum(pd);
    if (lane == 0) { a_s[wid] = ps; a_d[wid] = pd; }
}

// One wave per dst node. Segment softmax over incoming edges + self loop,
// then weighted gather of xl[src]. Each lane owns 2 channels (float2).
__global__ __launch_bounds__(256) void k_aggregate(const float* __restrict__ xl,
                                                   const float* __restrict__ a_s,
                                                   const float* __restrict__ a_d,
                                                   const int* __restrict__ csr_src,
                                                   const int* __restrict__ offsets,
                                                   const float* __restrict__ bias,
                                                   float* __restrict__ out, int n) {
    int wid = (blockIdx.x * blockDim.x + threadIdx.x) >> 6;
    int lane = threadIdx.x & 63;
    if (wid >= n) return;
    int beg = offsets[wid];
    int deg = offsets[wid + 1] - beg;
    float a_dn = a_d[wid];
    float e_self = lrelu(a_s[wid] + a_dn);

    // pass A: max
    float m_local = -INFINITY;
    float e_first = -INFINITY;
    int s_first = 0;
    for (int j = lane; j < deg; j += 64) {
        int s = csr_src[beg + j];
        float e = lrelu(a_s[s] + a_dn);
        if (j < 64) { e_first = e; s_first = s; }
        m_local = fmaxf(m_local, e);
    }
    float m = wred_max(fmaxf(m_local, e_self));

    // pass B: z
    float w_first = __expf(e_first - m);  // 0 for idle lanes (e_first = -inf)
    float zl = w_first;
    for (int j = 64 + lane; j < deg; j += 64) {
        int s = csr_src[beg + j];
        zl += __expf(lrelu(a_s[s] + a_dn) - m);
    }
    float w_self = __expf(e_self - m);
    float z = wred_sum(zl) + w_self;
    float inv = 1.0f / (z + 1e-16f);

    // pass C: weighted vector accumulate (2 channels per lane)
    const float2* xl2 = (const float2*)xl;
    float2 acc;
    {
        float2 v = xl2[(size_t)wid * 64 + lane];
        acc.x = w_self * v.x;
        acc.y = w_self * v.y;
    }
    int jmax = deg < 64 ? deg : 64;
    #pragma unroll 4
    for (int j = 0; j < jmax; ++j) {
        float w = __shfl(w_first, j);
        int s = __shfl(s_first, j);
        float2 v = xl2[(size_t)s * 64 + lane];
        acc.x += w * v.x;
        acc.y += w * v.y;
    }
    for (int j = 64; j < deg; ++j) {
        int s = csr_src[beg + j];  // uniform across wave
        float w = __expf(lrelu(a_s[s] + a_dn) - m);
        float2 v = xl2[(size_t)s * 64 + lane];
        acc.x += w * v.x;
        acc.y += w * v.y;
    }

    float2 bv = ((const float2*)bias)[lane];
    float2 r;
    r.x = fmaxf(acc.x * inv + bv.x, 0.0f);
    r.y = fmaxf(acc.y * inv + bv.y, 0.0f);
    ((float2*)out)[(size_t)wid * 64 + lane] = r;
}

extern "C" void kernel_launch(void* const* d_in, const int* in_sizes, int n_in,
                              void* d_out, int out_size, void* d_ws, size_t ws_size,
                              hipStream_t stream) {
    const float* x = (const float*)d_in[0];
    const int* edges = (const int*)d_in[1];
    const float* W1 = (const float*)d_in[2];
    const float* att_s1 = (const float*)d_in[3];
    const float* att_d1 = (const float*)d_in[4];
    const float* b1 = (const float*)d_in[5];
    const float* W2 = (const float*)d_in[6];
    const float* att_s2 = (const float*)d_in[7];
    const float* att_d2 = (const float*)d_in[8];
    const float* b2 = (const float*)d_in[9];

    const int N = in_sizes[0] / 128;
    const int E = in_sizes[1] / 2;
    const int* e_src = edges;
    const int* e_dst = edges + E;

    // workspace carve (256B aligned)
    char* w = (char*)d_ws;
    auto carve = [&](size_t bytes) {
        char* p = w;
        w += (bytes + 255) & ~(size_t)255;
        return p;
    };
    int* counts = (int*)carve((size_t)N * 4);
    int* offsets = (int*)carve((size_t)(N + 1) * 4);
    int* cursor = (int*)carve((size_t)N * 4);
    int* csr_src = (int*)carve((size_t)E * 4);
    float* a_s = (float*)carve((size_t)N * 4);
    float* a_d = (float*)carve((size_t)N * 4);
    float* xl = (float*)carve((size_t)N * 128 * 4);
    float* h = (float*)carve((size_t)N * 128 * 4);

    float* out = (float*)d_out;

    // CSR build (shared by both layers)
    k_zero<<<(N + 255) / 256, 256, 0, stream>>>(counts, N);
    k_hist<<<(E + 255) / 256, 256, 0, stream>>>(e_dst, E, counts);
    k_scan<<<1, 1024, 0, stream>>>(counts, offsets, cursor, N);
    k_scatter<<<(E + 255) / 256, 256, 0, stream>>>(e_src, e_dst, E, cursor, csr_src);

    int gemm_blocks = (N + 31) / 32;
    int wave_blocks = (N * 64 + 255) / 256;

    // layer 1
    k_gemm<<<gemm_blocks, 256, 0, stream>>>(x, W1, xl, N);
    k_attn<<<wave_blocks, 256, 0, stream>>>(xl, att_s1, att_d1, a_s, a_d, N);
    k_aggregate<<<wave_blocks, 256, 0, stream>>>(xl, a_s, a_d, csr_src, offsets, b1, h, N);

    // layer 2
    k_gemm<<<gemm_blocks, 256, 0, stream>>>(h, W2, xl, N);
    k_attn<<<wave_blocks, 256, 0, stream>>>(xl, att_s2, att_d2, a_s, a_d, N);
    k_aggregate<<<wave_blocks, 256, 0, stream>>>(xl, a_s, a_d, csr_src, offsets, b2, out, N);
}

// Round 3
// 295.633 us; speedup vs baseline: 1.1999x; 1.1999x over previous
//
#include <hip/hip_runtime.h>
#include <hip/hip_bf16.h>
#include <math.h>

#define NEG_SLOPE 0.2f

__device__ __forceinline__ float lrelu(float v) {
    return v > 0.0f ? v : NEG_SLOPE * v;
}

__device__ __forceinline__ float wred_sum(float v) {
    #pragma unroll
    for (int d = 32; d; d >>= 1) v += __shfl_xor(v, d);
    return v;
}

__global__ void k_hist(const int* __restrict__ dst, int E, int* __restrict__ counts) {
    int i = blockIdx.x * blockDim.x + threadIdx.x;
    if (i < E) atomicAdd(&counts[dst[i]], 1);
}

// Single-block exclusive scan, 4 elements/thread. offsets[0..n] + cursor copy.
__global__ __launch_bounds__(1024) void k_scan(const int* __restrict__ counts,
                                               int* __restrict__ offsets,
                                               int* __restrict__ cursor, int n) {
    __shared__ int wsums[16];
    __shared__ int carry_sh;
    int tid = threadIdx.x;
    int lane = tid & 63;
    int wv = tid >> 6;
    if (tid == 0) carry_sh = 0;
    __syncthreads();
    int n4 = (n + 3) >> 2;
    for (int base = 0; base < n4; base += 1024) {
        int i = base + tid;
        int e0 = i << 2;
        int v0 = 0, v1 = 0, v2 = 0, v3 = 0;
        if (e0 + 3 < n) {
            int4 c = ((const int4*)counts)[i];
            v0 = c.x; v1 = c.y; v2 = c.z; v3 = c.w;
        } else if (e0 < n) {
            v0 = counts[e0];
            if (e0 + 1 < n) v1 = counts[e0 + 1];
            if (e0 + 2 < n) v2 = counts[e0 + 2];
        }
        int p1 = v0, p2 = p1 + v1, p3 = p2 + v2, tot = p3 + v3;
        int x = tot;
        #pragma unroll
        for (int d = 1; d < 64; d <<= 1) {
            int y = __shfl_up(x, d);
            if (lane >= d) x += y;
        }
        if (lane == 63) wsums[wv] = x;
        __syncthreads();
        if (wv == 0) {
            int s = (lane < 16) ? wsums[lane] : 0;
            #pragma unroll
            for (int d = 1; d < 16; d <<= 1) {
                int y = __shfl_up(s, d);
                if (lane >= d) s += y;
            }
            if (lane < 16) wsums[lane] = s;
        }
        __syncthreads();
        int excl = carry_sh + (wv > 0 ? wsums[wv - 1] : 0) + (x - tot);
        if (e0 + 3 < n) {
            int4 o = make_int4(excl, excl + p1, excl + p2, excl + p3);
            ((int4*)offsets)[i] = o;
            ((int4*)cursor)[i] = o;
        } else if (e0 < n) {
            offsets[e0] = excl; cursor[e0] = excl;
            if (e0 + 1 < n) { offsets[e0 + 1] = excl + p1; cursor[e0 + 1] = excl + p1; }
            if (e0 + 2 < n) { offsets[e0 + 2] = excl + p2; cursor[e0 + 2] = excl + p2; }
        }
        __syncthreads();
        if (tid == 0) carry_sh += wsums[15];
        __syncthreads();
    }
    if (tid == 0) offsets[n] = carry_sh;
}

__global__ void k_scatter(const int* __restrict__ src, const int* __restrict__ dst,
                          int E, int* __restrict__ cursor, int* __restrict__ csr_src) {
    int i = blockIdx.x * blockDim.x + threadIdx.x;
    if (i < E) {
        int d = dst[i];
        int pos = atomicAdd(&cursor[d], 1);
        csr_src[pos] = src[i];
    }
}

// XL[n,128] = X[n,128] @ W[128,128] (f32), fused a_s/a_d epilogue.
// Block: 256 thr, 32 rows x 128 cols, 4x4 register blocking.
__global__ __launch_bounds__(256) void k_gemm_attn(const float* __restrict__ X,
                                                   const float* __restrict__ W,
                                                   const float* __restrict__ att_s,
                                                   const float* __restrict__ att_d,
                                                   float* __restrict__ XL,
                                                   float* __restrict__ a_s,
                                                   float* __restrict__ a_d, int n) {
    __shared__ float Wl[64 * 128];  // 32KB
    __shared__ float Xl[32 * 128];  // 16KB
    int tid = threadIdx.x;
    int row0 = blockIdx.x * 32;
    {
        const float4* X4 = (const float4*)X;
        float4* Xl4 = (float4*)Xl;
        for (int i = tid; i < 32 * 32; i += 256) {
            int r = i >> 5;
            int gr = row0 + r;
            Xl4[i] = (gr < n) ? X4[(size_t)gr * 32 + (i & 31)] : make_float4(0, 0, 0, 0);
        }
    }
    int tc = tid & 31, tr = tid >> 5;
    float acc[4][4] = {};
    for (int kb = 0; kb < 128; kb += 64) {
        __syncthreads();
        const float4* W4 = (const float4*)(W + (size_t)kb * 128);
        float4* Wl4 = (float4*)Wl;
        for (int i = tid; i < 2048; i += 256) Wl4[i] = W4[i];
        __syncthreads();
        #pragma unroll 8
        for (int kk = 0; kk < 64; ++kk) {
            int k = kb + kk;
            float4 wv = *(const float4*)&Wl[kk * 128 + tc * 4];
            float xv[4];
            #pragma unroll
            for (int i = 0; i < 4; i++) xv[i] = Xl[(tr * 4 + i) * 128 + k];
            #pragma unroll
            for (int i = 0; i < 4; i++) {
                acc[i][0] += xv[i] * wv.x;
                acc[i][1] += xv[i] * wv.y;
                acc[i][2] += xv[i] * wv.z;
                acc[i][3] += xv[i] * wv.w;
            }
        }
    }
    // fused attention dots: a_s[r] = xl[r,:]·att_s, a_d[r] = xl[r,:]·att_d
    float4 as4 = ((const float4*)att_s)[tc];
    float4 ad4 = ((const float4*)att_d)[tc];
    #pragma unroll
    for (int i = 0; i < 4; i++) {
        float ps = acc[i][0] * as4.x + acc[i][1] * as4.y + acc[i][2] * as4.z + acc[i][3] * as4.w;
        float pd = acc[i][0] * ad4.x + acc[i][1] * ad4.y + acc[i][2] * ad4.z + acc[i][3] * ad4.w;
        #pragma unroll
        for (int d = 16; d; d >>= 1) { ps += __shfl_xor(ps, d); pd += __shfl_xor(pd, d); }
        int r = row0 + tr * 4 + i;
        if (tc == 0 && r < n) { a_s[r] = ps; a_d[r] = pd; }
    }
    #pragma unroll
    for (int i = 0; i < 4; i++) {
        int r = row0 + tr * 4 + i;
        if (r < n)
            *(float4*)&XL[(size_t)r * 128 + tc * 4] =
                make_float4(acc[i][0], acc[i][1], acc[i][2], acc[i][3]);
    }
}

// One wave per dst node. Softmax WITHOUT max-subtraction (shift-invariant;
// logits bounded ~|10| here, exp safe in f32). Two 32-lane halves process
// alternate edges with float4 gathers. The gather loop trip count is WAVE-
// UNIFORM (nt = ceil(jmax/2) for both halves) so every __shfl executes with
// all 64 lanes active — shfl from an exec-masked lane is undefined on CDNA.
__global__ __launch_bounds__(256) void k_aggregate(const float* __restrict__ xl,
                                                   const float* __restrict__ a_s,
                                                   const float* __restrict__ a_d,
                                                   const int* __restrict__ csr_src,
                                                   const int* __restrict__ offsets,
                                                   const float* __restrict__ bias,
                                                   float* __restrict__ out, int n) {
    int wid = (blockIdx.x * blockDim.x + threadIdx.x) >> 6;
    int lane = threadIdx.x & 63;
    if (wid >= n) return;
    int beg = offsets[wid];
    int deg = offsets[wid + 1] - beg;
    float a_dn = a_d[wid];
    float w_self = __expf(lrelu(a_s[wid] + a_dn));

    // per-lane weight for the first 64 edges (covers ~all nodes: avg deg 16)
    int s_l = 0;
    float w_l = 0.0f;
    if (lane < deg) {
        s_l = csr_src[beg + lane];
        w_l = __expf(lrelu(a_s[s_l] + a_dn));
    }
    float zl = w_l;
    for (int j = 64 + lane; j < deg; j += 64) {
        int s = csr_src[beg + j];
        zl += __expf(lrelu(a_s[s] + a_dn));
    }
    float z = wred_sum(zl) + w_self;
    float inv = 1.0f / (z + 1e-16f);

    // weighted row gather: half h handles edges j = h, h+2, h+4, ...
    int half = lane >> 5, cl = lane & 31;
    const float4* xl4 = (const float4*)xl;
    float4 acc = make_float4(0.0f, 0.0f, 0.0f, 0.0f);
    if (half == 0) {
        float4 v = xl4[(size_t)wid * 32 + cl];
        acc.x = w_self * v.x; acc.y = w_self * v.y;
        acc.z = w_self * v.z; acc.w = w_self * v.w;
    }
    int jmax = deg < 64 ? deg : 64;
    int nt = (jmax + 1) >> 1;  // uniform trip count across the wave
    for (int t = 0; t < nt; ++t) {
        int j = (t << 1) + half;
        int jj = j < jmax ? j : 0;       // clamped: shfl always well-defined
        float wj = __shfl(w_l, jj);
        int sj = __shfl(s_l, jj);
        if (j < jmax) {
            float4 v = xl4[(size_t)sj * 32 + cl];
            acc.x += wj * v.x; acc.y += wj * v.y;
            acc.z += wj * v.z; acc.w += wj * v.w;
        }
    }
    for (int j = 64 + half; j < deg; j += 2) {  // rare tail (deg > 64), no shfl
        int sj = csr_src[beg + j];
        float wj = __expf(lrelu(a_s[sj] + a_dn));
        float4 v = xl4[(size_t)sj * 32 + cl];
        acc.x += wj * v.x; acc.y += wj * v.y;
        acc.z += wj * v.z; acc.w += wj * v.w;
    }
    // combine the two halves
    acc.x += __shfl_xor(acc.x, 32);
    acc.y += __shfl_xor(acc.y, 32);
    acc.z += __shfl_xor(acc.z, 32);
    acc.w += __shfl_xor(acc.w, 32);
    if (half == 0) {
        float4 bv = ((const float4*)bias)[cl];
        float4 r;
        r.x = fmaxf(acc.x * inv + bv.x, 0.0f);
        r.y = fmaxf(acc.y * inv + bv.y, 0.0f);
        r.z = fmaxf(acc.z * inv + bv.z, 0.0f);
        r.w = fmaxf(acc.w * inv + bv.w, 0.0f);
        ((float4*)out)[(size_t)wid * 32 + cl] = r;
    }
}

extern "C" void kernel_launch(void* const* d_in, const int* in_sizes, int n_in,
                              void* d_out, int out_size, void* d_ws, size_t ws_size,
                              hipStream_t stream) {
    const float* x = (const float*)d_in[0];
    const int* edges = (const int*)d_in[1];
    const float* W1 = (const float*)d_in[2];
    const float* att_s1 = (const float*)d_in[3];
    const float* att_d1 = (const float*)d_in[4];
    const float* b1 = (const float*)d_in[5];
    const float* W2 = (const float*)d_in[6];
    const float* att_s2 = (const float*)d_in[7];
    const float* att_d2 = (const float*)d_in[8];
    const float* b2 = (const float*)d_in[9];

    const int N = in_sizes[0] / 128;
    const int E = in_sizes[1] / 2;
    const int* e_src = edges;
    const int* e_dst = edges + E;

    char* w = (char*)d_ws;
    auto carve = [&](size_t bytes) {
        char* p = w;
        w += (bytes + 255) & ~(size_t)255;
        return p;
    };
    int* counts = (int*)carve((size_t)N * 4);
    int* offsets = (int*)carve((size_t)(N + 1) * 4);
    int* cursor = (int*)carve((size_t)N * 4);
    int* csr_src = (int*)carve((size_t)E * 4);
    float* a_s = (float*)carve((size_t)N * 4);
    float* a_d = (float*)carve((size_t)N * 4);
    float* xl = (float*)carve((size_t)N * 128 * 4);
    float* h = (float*)carve((size_t)N * 128 * 4);

    float* out = (float*)d_out;

    // CSR build (shared by both layers)
    hipMemsetAsync(counts, 0, (size_t)N * 4, stream);
    k_hist<<<(E + 255) / 256, 256, 0, stream>>>(e_dst, E, counts);
    k_scan<<<1, 1024, 0, stream>>>(counts, offsets, cursor, N);
    k_scatter<<<(E + 255) / 256, 256, 0, stream>>>(e_src, e_dst, E, cursor, csr_src);

    int gemm_blocks = (N + 31) / 32;
    int wave_blocks = (N * 64 + 255) / 256;

    // layer 1
    k_gemm_attn<<<gemm_blocks, 256, 0, stream>>>(x, W1, att_s1, att_d1, xl, a_s, a_d, N);
    k_aggregate<<<wave_blocks, 256, 0, stream>>>(xl, a_s, a_d, csr_src, offsets, b1, h, N);

    // layer 2
    k_gemm_attn<<<gemm_blocks, 256, 0, stream>>>(h, W2, att_s2, att_d2, xl, a_s, a_d, N);
    k_aggregate<<<wave_blocks, 256, 0, stream>>>(xl, a_s, a_d, csr_src, offsets, b2, out, N);
}

// Round 4
// 257.233 us; speedup vs baseline: 1.3790x; 1.1493x over previous
//
#include <hip/hip_runtime.h>
#include <hip/hip_bf16.h>
#include <math.h>

#define NEG_SLOPE 0.2f

__device__ __forceinline__ float lrelu(float v) {
    return v > 0.0f ? v : NEG_SLOPE * v;
}

__device__ __forceinline__ float wred_sum(float v) {
    #pragma unroll
    for (int d = 32; d; d >>= 1) v += __shfl_xor(v, d);
    return v;
}

__device__ __forceinline__ unsigned short f2bf(float f) {  // RNE f32->bf16
    unsigned u = __float_as_uint(f);
    return (unsigned short)((u + 0x7FFFu + ((u >> 16) & 1u)) >> 16);
}

__device__ __forceinline__ void bf8_fma(float* acc, uint4 u, float w) {
    acc[0] += w * __uint_as_float(u.x << 16);
    acc[1] += w * __uint_as_float(u.x & 0xFFFF0000u);
    acc[2] += w * __uint_as_float(u.y << 16);
    acc[3] += w * __uint_as_float(u.y & 0xFFFF0000u);
    acc[4] += w * __uint_as_float(u.z << 16);
    acc[5] += w * __uint_as_float(u.z & 0xFFFF0000u);
    acc[6] += w * __uint_as_float(u.w << 16);
    acc[7] += w * __uint_as_float(u.w & 0xFFFF0000u);
}

__global__ void k_hist(const int* __restrict__ dst, int E, int* __restrict__ counts) {
    int i = blockIdx.x * blockDim.x + threadIdx.x;
    if (i < E) atomicAdd(&counts[dst[i]], 1);
}

// Single-block exclusive scan, 4 elements/thread. offsets[0..n] + cursor copy.
__global__ __launch_bounds__(1024) void k_scan(const int* __restrict__ counts,
                                               int* __restrict__ offsets,
                                               int* __restrict__ cursor, int n) {
    __shared__ int wsums[16];
    __shared__ int carry_sh;
    int tid = threadIdx.x;
    int lane = tid & 63;
    int wv = tid >> 6;
    if (tid == 0) carry_sh = 0;
    __syncthreads();
    int n4 = (n + 3) >> 2;
    for (int base = 0; base < n4; base += 1024) {
        int i = base + tid;
        int e0 = i << 2;
        int v0 = 0, v1 = 0, v2 = 0, v3 = 0;
        if (e0 + 3 < n) {
            int4 c = ((const int4*)counts)[i];
            v0 = c.x; v1 = c.y; v2 = c.z; v3 = c.w;
        } else if (e0 < n) {
            v0 = counts[e0];
            if (e0 + 1 < n) v1 = counts[e0 + 1];
            if (e0 + 2 < n) v2 = counts[e0 + 2];
        }
        int p1 = v0, p2 = p1 + v1, p3 = p2 + v2, tot = p3 + v3;
        int x = tot;
        #pragma unroll
        for (int d = 1; d < 64; d <<= 1) {
            int y = __shfl_up(x, d);
            if (lane >= d) x += y;
        }
        if (lane == 63) wsums[wv] = x;
        __syncthreads();
        if (wv == 0) {
            int s = (lane < 16) ? wsums[lane] : 0;
            #pragma unroll
            for (int d = 1; d < 16; d <<= 1) {
                int y = __shfl_up(s, d);
                if (lane >= d) s += y;
            }
            if (lane < 16) wsums[lane] = s;
        }
        __syncthreads();
        int excl = carry_sh + (wv > 0 ? wsums[wv - 1] : 0) + (x - tot);
        if (e0 + 3 < n) {
            int4 o = make_int4(excl, excl + p1, excl + p2, excl + p3);
            ((int4*)offsets)[i] = o;
            ((int4*)cursor)[i] = o;
        } else if (e0 < n) {
            offsets[e0] = excl; cursor[e0] = excl;
            if (e0 + 1 < n) { offsets[e0 + 1] = excl + p1; cursor[e0 + 1] = excl + p1; }
            if (e0 + 2 < n) { offsets[e0 + 2] = excl + p2; cursor[e0 + 2] = excl + p2; }
        }
        __syncthreads();
        if (tid == 0) carry_sh += wsums[15];
        __syncthreads();
    }
    if (tid == 0) offsets[n] = carry_sh;
}

__global__ void k_scatter(const int* __restrict__ src, const int* __restrict__ dst,
                          int E, int* __restrict__ cursor, int* __restrict__ csr_src) {
    int i = blockIdx.x * blockDim.x + threadIdx.x;
    if (i < E) {
        int d = dst[i];
        int pos = atomicAdd(&cursor[d], 1);
        csr_src[pos] = src[i];
    }
}

// XL_bf16[n,128] = X[n,128] @ W[128,128] (f32 math, bf16 store), fused
// a_s/a_d epilogue (computed from f32 accumulators).
// Block: 256 thr, tile 128 rows x 128 cols, 8x8 register blocking, K halves
// of 64. X tile staged TRANSPOSED (k-major) with XOR swizzle
// r' = r ^ (((k>>2)&7)<<2): staging writes 2-way (free, m136), xv reads
// conflict-free, 16B alignment preserved (swizzle only touches elem bits 2-4).
__global__ __launch_bounds__(256) void k_gemm_attn(const float* __restrict__ X,
                                                   const float* __restrict__ W,
                                                   const float* __restrict__ att_s,
                                                   const float* __restrict__ att_d,
                                                   unsigned short* __restrict__ XLb,
                                                   float* __restrict__ a_s,
                                                   float* __restrict__ a_d, int n) {
    __shared__ float XT[64 * 128];  // 32 KB, XT[k*128 + (r^sw(k))]
    __shared__ float Wl[64 * 128];  // 32 KB, Wl[k*128 + col]
    int tid = threadIdx.x;
    int row0 = blockIdx.x * 128;
    int c = tid & 15;   // col group: cols c*4..+3 and 64+c*4..+3
    int rg = tid >> 4;  // row group: rows rg*8..rg*8+7

    float acc[8][8] = {};
    for (int kb = 0; kb < 128; kb += 64) {
        __syncthreads();
        {   // stage W K-half (straight copy, coalesced, conflict-free)
            const float4* W4 = (const float4*)(W + (size_t)kb * 128);
            float4* Wl4 = (float4*)Wl;
            #pragma unroll
            for (int i = 0; i < 8; ++i) Wl4[tid + i * 256] = W4[tid + i * 256];
        }
        {   // stage X transposed + swizzled
            #pragma unroll
            for (int it = 0; it < 8; ++it) {
                int idx = tid + it * 256;  // 0..2047
                int r = idx >> 4;          // 0..127
                int kq = idx & 15;         // float4 index within K-half
                int gr = row0 + r;
                float4 v = (gr < n) ? ((const float4*)X)[(size_t)gr * 32 + (kb >> 2) + kq]
                                    : make_float4(0.f, 0.f, 0.f, 0.f);
                int rs = r ^ ((kq & 7) << 2);  // (k>>2)&7 == kq&7 for k=kq*4+j
                float* dstp = &XT[(kq * 4) * 128 + rs];
                dstp[0 * 128] = v.x;
                dstp[1 * 128] = v.y;
                dstp[2 * 128] = v.z;
                dstp[3 * 128] = v.w;
            }
        }
        __syncthreads();
        #pragma unroll 2
        for (int kk = 0; kk < 64; ++kk) {
            int sw = ((kk >> 2) & 7) << 2;
            const float* xt = &XT[kk * 128];
            float4 xa = *(const float4*)&xt[(rg * 8) ^ sw];
            float4 xb = *(const float4*)&xt[(rg * 8 + 4) ^ sw];
            const float* wr = &Wl[kk * 128];
            float4 wa = *(const float4*)&wr[c * 4];
            float4 wb = *(const float4*)&wr[64 + c * 4];
            float xv[8] = {xa.x, xa.y, xa.z, xa.w, xb.x, xb.y, xb.z, xb.w};
            float wv[8] = {wa.x, wa.y, wa.z, wa.w, wb.x, wb.y, wb.z, wb.w};
            #pragma unroll
            for (int i = 0; i < 8; ++i)
                #pragma unroll
                for (int j = 0; j < 8; ++j)
                    acc[i][j] += xv[i] * wv[j];
        }
    }

    // fused attention dots from f32 accumulators
    float4 as_a = ((const float4*)att_s)[c];
    float4 as_b = ((const float4*)att_s)[16 + c];
    float4 ad_a = ((const float4*)att_d)[c];
    float4 ad_b = ((const float4*)att_d)[16 + c];
    float asv[8] = {as_a.x, as_a.y, as_a.z, as_a.w, as_b.x, as_b.y, as_b.z, as_b.w};
    float adv[8] = {ad_a.x, ad_a.y, ad_a.z, ad_a.w, ad_b.x, ad_b.y, ad_b.z, ad_b.w};
    #pragma unroll
    for (int i = 0; i < 8; ++i) {
        float ps = 0.f, pd = 0.f;
        #pragma unroll
        for (int j = 0; j < 8; ++j) { ps += acc[i][j] * asv[j]; pd += acc[i][j] * adv[j]; }
        #pragma unroll
        for (int d = 1; d < 16; d <<= 1) { ps += __shfl_xor(ps, d); pd += __shfl_xor(pd, d); }
        int r = row0 + rg * 8 + i;
        if (c == 0 && r < n) { a_s[r] = ps; a_d[r] = pd; }
    }
    // bf16 store of XL (gather operand)
    #pragma unroll
    for (int i = 0; i < 8; ++i) {
        int r = row0 + rg * 8 + i;
        if (r < n) {
            unsigned p0 = ((unsigned)f2bf(acc[i][1]) << 16) | f2bf(acc[i][0]);
            unsigned p1 = ((unsigned)f2bf(acc[i][3]) << 16) | f2bf(acc[i][2]);
            unsigned p2 = ((unsigned)f2bf(acc[i][5]) << 16) | f2bf(acc[i][4]);
            unsigned p3 = ((unsigned)f2bf(acc[i][7]) << 16) | f2bf(acc[i][6]);
            uint2* o = (uint2*)(XLb + (size_t)r * 128);
            o[c] = make_uint2(p0, p1);       // cols c*4..c*4+3
            o[16 + c] = make_uint2(p2, p3);  // cols 64+c*4..+3
        }
    }
}

// One wave per dst node. No-max softmax (logits bounded, exp safe in f32).
// Four 16-lane groups process 4 edges/iter; each lane loads uint4 = 8 bf16
// channels (16B). Gather loop trip count is WAVE-UNIFORM with clamped shfl
// index (shfl from exec-masked lanes is undefined on CDNA). Tail (deg>64)
// has no shfl, so divergent trip counts are safe there.
__global__ __launch_bounds__(256) void k_aggregate(const unsigned short* __restrict__ xlb,
                                                   const float* __restrict__ a_s,
                                                   const float* __restrict__ a_d,
                                                   const int* __restrict__ csr_src,
                                                   const int* __restrict__ offsets,
                                                   const float* __restrict__ bias,
                                                   float* __restrict__ out, int n) {
    int wid = (blockIdx.x * blockDim.x + threadIdx.x) >> 6;
    int lane = threadIdx.x & 63;
    if (wid >= n) return;
    int beg = offsets[wid];
    int deg = offsets[wid + 1] - beg;
    float a_dn = a_d[wid];
    float w_self = __expf(lrelu(a_s[wid] + a_dn));

    int s_l = 0;
    float w_l = 0.0f;
    if (lane < deg) {
        s_l = csr_src[beg + lane];
        w_l = __expf(lrelu(a_s[s_l] + a_dn));
    }
    float zl = w_l;
    for (int j = 64 + lane; j < deg; j += 64) {
        int s = csr_src[beg + j];
        zl += __expf(lrelu(a_s[s] + a_dn));
    }
    float z = wred_sum(zl) + w_self;
    float inv = 1.0f / (z + 1e-16f);

    int qw = lane >> 4, ql = lane & 15;
    const uint4* xb4 = (const uint4*)xlb;  // row = 16 x uint4 (256B)
    float acc[8] = {};
    if (qw == 0) {  // self loop handled by group 0
        uint4 u = xb4[(size_t)wid * 16 + ql];
        bf8_fma(acc, u, w_self);
    }
    int jmax = deg < 64 ? deg : 64;
    int nt = (jmax + 3) >> 2;  // uniform trip count across the wave
    for (int t = 0; t < nt; ++t) {
        int j = (t << 2) + qw;
        int jj = j < jmax ? j : 0;  // clamped: shfl always well-defined
        float wj = __shfl(w_l, jj);
        int sj = __shfl(s_l, jj);
        if (j < jmax) {
            uint4 u = xb4[(size_t)sj * 16 + ql];
            bf8_fma(acc, u, wj);
        }
    }
    for (int j = 64 + qw; j < deg; j += 4) {  // rare tail, no shfl
        int sj = csr_src[beg + j];
        float wj = __expf(lrelu(a_s[sj] + a_dn));
        uint4 u = xb4[(size_t)sj * 16 + ql];
        bf8_fma(acc, u, wj);
    }
    #pragma unroll
    for (int k = 0; k < 8; ++k) {
        acc[k] += __shfl_xor(acc[k], 16);
        acc[k] += __shfl_xor(acc[k], 32);
    }
    if (qw == 0) {
        float4 b0 = ((const float4*)bias)[ql * 2];
        float4 b1 = ((const float4*)bias)[ql * 2 + 1];
        float4 r0, r1;
        r0.x = fmaxf(acc[0] * inv + b0.x, 0.0f);
        r0.y = fmaxf(acc[1] * inv + b0.y, 0.0f);
        r0.z = fmaxf(acc[2] * inv + b0.z, 0.0f);
        r0.w = fmaxf(acc[3] * inv + b0.w, 0.0f);
        r1.x = fmaxf(acc[4] * inv + b1.x, 0.0f);
        r1.y = fmaxf(acc[5] * inv + b1.y, 0.0f);
        r1.z = fmaxf(acc[6] * inv + b1.z, 0.0f);
        r1.w = fmaxf(acc[7] * inv + b1.w, 0.0f);
        ((float4*)out)[(size_t)wid * 32 + ql * 2] = r0;
        ((float4*)out)[(size_t)wid * 32 + ql * 2 + 1] = r1;
    }
}

extern "C" void kernel_launch(void* const* d_in, const int* in_sizes, int n_in,
                              void* d_out, int out_size, void* d_ws, size_t ws_size,
                              hipStream_t stream) {
    const float* x = (const float*)d_in[0];
    const int* edges = (const int*)d_in[1];
    const float* W1 = (const float*)d_in[2];
    const float* att_s1 = (const float*)d_in[3];
    const float* att_d1 = (const float*)d_in[4];
    const float* b1 = (const float*)d_in[5];
    const float* W2 = (const float*)d_in[6];
    const float* att_s2 = (const float*)d_in[7];
    const float* att_d2 = (const float*)d_in[8];
    const float* b2 = (const float*)d_in[9];

    const int N = in_sizes[0] / 128;
    const int E = in_sizes[1] / 2;
    const int* e_src = edges;
    const int* e_dst = edges + E;

    char* w = (char*)d_ws;
    auto carve = [&](size_t bytes) {
        char* p = w;
        w += (bytes + 255) & ~(size_t)255;
        return p;
    };
    int* counts = (int*)carve((size_t)N * 4);
    int* offsets = (int*)carve((size_t)(N + 1) * 4);
    int* cursor = (int*)carve((size_t)N * 4);
    int* csr_src = (int*)carve((size_t)E * 4);
    float* a_s = (float*)carve((size_t)N * 4);
    float* a_d = (float*)carve((size_t)N * 4);
    unsigned short* xlb = (unsigned short*)carve((size_t)N * 128 * 2);
    float* h = (float*)carve((size_t)N * 128 * 4);

    float* out = (float*)d_out;

    // CSR build (shared by both layers)
    hipMemsetAsync(counts, 0, (size_t)N * 4, stream);
    k_hist<<<(E + 255) / 256, 256, 0, stream>>>(e_dst, E, counts);
    k_scan<<<1, 1024, 0, stream>>>(counts, offsets, cursor, N);
    k_scatter<<<(E + 255) / 256, 256, 0, stream>>>(e_src, e_dst, E, cursor, csr_src);

    int gemm_blocks = (N + 127) / 128;
    int wave_blocks = (N * 64 + 255) / 256;

    // layer 1
    k_gemm_attn<<<gemm_blocks, 256, 0, stream>>>(x, W1, att_s1, att_d1, xlb, a_s, a_d, N);
    k_aggregate<<<wave_blocks, 256, 0, stream>>>(xlb, a_s, a_d, csr_src, offsets, b1, h, N);

    // layer 2 (xlb reused; agg1 finishes before gemm2 overwrites it)
    k_gemm_attn<<<gemm_blocks, 256, 0, stream>>>(h, W2, att_s2, att_d2, xlb, a_s, a_d, N);
    k_aggregate<<<wave_blocks, 256, 0, stream>>>(xlb, a_s, a_d, csr_src, offsets, b2, out, N);
}

// Round 5
// 222.524 us; speedup vs baseline: 1.5941x; 1.1560x over previous
//
#include <hip/hip_runtime.h>
#include <hip/hip_bf16.h>
#include <math.h>

#define NEG_SLOPE 0.2f

__device__ __forceinline__ float lrelu(float v) {
    return v > 0.0f ? v : NEG_SLOPE * v;
}

__device__ __forceinline__ float wred_sum(float v) {
    #pragma unroll
    for (int d = 32; d; d >>= 1) v += __shfl_xor(v, d);
    return v;
}

__device__ __forceinline__ unsigned short f2bf(float f) {  // RNE f32->bf16
    unsigned u = __float_as_uint(f);
    return (unsigned short)((u + 0x7FFFu + ((u >> 16) & 1u)) >> 16);
}

__device__ __forceinline__ void bf8_fma(float* acc, uint4 u, float w) {
    acc[0] += w * __uint_as_float(u.x << 16);
    acc[1] += w * __uint_as_float(u.x & 0xFFFF0000u);
    acc[2] += w * __uint_as_float(u.y << 16);
    acc[3] += w * __uint_as_float(u.y & 0xFFFF0000u);
    acc[4] += w * __uint_as_float(u.z << 16);
    acc[5] += w * __uint_as_float(u.z & 0xFFFF0000u);
    acc[6] += w * __uint_as_float(u.w << 16);
    acc[7] += w * __uint_as_float(u.w & 0xFFFF0000u);
}

// Histogram + rank capture: atomicAdd's return value IS this edge's rank
// within its dst segment. Rank stored coalesced. 4 edges/thread for MLP.
__global__ void k_hist_rank(const int* __restrict__ dst, int E,
                            int* __restrict__ counts, int* __restrict__ rank) {
    int i = blockIdx.x * blockDim.x + threadIdx.x;
    int base = i << 2;
    if (base + 3 < E) {
        int4 d = ((const int4*)dst)[i];
        int4 r;
        r.x = atomicAdd(&counts[d.x], 1);
        r.y = atomicAdd(&counts[d.y], 1);
        r.z = atomicAdd(&counts[d.z], 1);
        r.w = atomicAdd(&counts[d.w], 1);
        ((int4*)rank)[i] = r;
    } else {
        for (int j = base; j < E; ++j) rank[j] = atomicAdd(&counts[dst[j]], 1);
    }
}

// Scalar fallback (unaligned / arbitrary E)
__global__ void k_hist_rank_s(const int* __restrict__ dst, int E,
                              int* __restrict__ counts, int* __restrict__ rank) {
    int i = blockIdx.x * blockDim.x + threadIdx.x;
    if (i < E) rank[i] = atomicAdd(&counts[dst[i]], 1);
}

// Single-block exclusive scan, 4 elements/thread -> offsets[0..n].
__global__ __launch_bounds__(1024) void k_scan(const int* __restrict__ counts,
                                               int* __restrict__ offsets, int n) {
    __shared__ int wsums[16];
    __shared__ int carry_sh;
    int tid = threadIdx.x;
    int lane = tid & 63;
    int wv = tid >> 6;
    if (tid == 0) carry_sh = 0;
    __syncthreads();
    int n4 = (n + 3) >> 2;
    for (int base = 0; base < n4; base += 1024) {
        int i = base + tid;
        int e0 = i << 2;
        int v0 = 0, v1 = 0, v2 = 0, v3 = 0;
        if (e0 + 3 < n) {
            int4 c = ((const int4*)counts)[i];
            v0 = c.x; v1 = c.y; v2 = c.z; v3 = c.w;
        } else if (e0 < n) {
            v0 = counts[e0];
            if (e0 + 1 < n) v1 = counts[e0 + 1];
            if (e0 + 2 < n) v2 = counts[e0 + 2];
        }
        int p1 = v0, p2 = p1 + v1, p3 = p2 + v2, tot = p3 + v3;
        int x = tot;
        #pragma unroll
        for (int d = 1; d < 64; d <<= 1) {
            int y = __shfl_up(x, d);
            if (lane >= d) x += y;
        }
        if (lane == 63) wsums[wv] = x;
        __syncthreads();
        if (wv == 0) {
            int s = (lane < 16) ? wsums[lane] : 0;
            #pragma unroll
            for (int d = 1; d < 16; d <<= 1) {
                int y = __shfl_up(s, d);
                if (lane >= d) s += y;
            }
            if (lane < 16) wsums[lane] = s;
        }
        __syncthreads();
        int excl = carry_sh + (wv > 0 ? wsums[wv - 1] : 0) + (x - tot);
        if (e0 + 3 < n) {
            ((int4*)offsets)[i] = make_int4(excl, excl + p1, excl + p2, excl + p3);
        } else if (e0 < n) {
            offsets[e0] = excl;
            if (e0 + 1 < n) offsets[e0 + 1] = excl + p1;
            if (e0 + 2 < n) offsets[e0 + 2] = excl + p2;
        }
        __syncthreads();
        if (tid == 0) carry_sh += wsums[15];
        __syncthreads();
    }
    if (tid == 0) offsets[n] = carry_sh;
}

// Atomic-free scatter: position = offsets[dst] + rank. 4 edges/thread.
__global__ void k_scatter(const int* __restrict__ src, const int* __restrict__ dst,
                          const int* __restrict__ rank, const int* __restrict__ offsets,
                          int E, int* __restrict__ csr_src) {
    int i = blockIdx.x * blockDim.x + threadIdx.x;
    int base = i << 2;
    if (base + 3 < E) {
        int4 s = ((const int4*)src)[i];
        int4 d = ((const int4*)dst)[i];
        int4 r = ((const int4*)rank)[i];
        csr_src[offsets[d.x] + r.x] = s.x;
        csr_src[offsets[d.y] + r.y] = s.y;
        csr_src[offsets[d.z] + r.z] = s.z;
        csr_src[offsets[d.w] + r.w] = s.w;
    } else {
        for (int j = base; j < E; ++j) csr_src[offsets[dst[j]] + rank[j]] = src[j];
    }
}

__global__ void k_scatter_s(const int* __restrict__ src, const int* __restrict__ dst,
                            const int* __restrict__ rank, const int* __restrict__ offsets,
                            int E, int* __restrict__ csr_src) {
    int i = blockIdx.x * blockDim.x + threadIdx.x;
    if (i < E) csr_src[offsets[dst[i]] + rank[i]] = src[i];
}

// XL_bf16[n,128] = X[n,128] @ W[128,128] (f32 math, bf16 store), fused
// a_s/a_d epilogue (computed from f32 accumulators).
// Block: 256 thr, tile 128 rows x 128 cols, 8x8 register blocking, K halves
// of 64. X tile staged TRANSPOSED (k-major) with XOR swizzle
// r' = r ^ (((k>>2)&7)<<2): staging writes 2-way (free, m136), xv reads
// conflict-free, 16B alignment preserved (swizzle only touches elem bits 2-4).
__global__ __launch_bounds__(256) void k_gemm_attn(const float* __restrict__ X,
                                                   const float* __restrict__ W,
                                                   const float* __restrict__ att_s,
                                                   const float* __restrict__ att_d,
                                                   unsigned short* __restrict__ XLb,
                                                   float* __restrict__ a_s,
                                                   float* __restrict__ a_d, int n) {
    __shared__ float XT[64 * 128];  // 32 KB, XT[k*128 + (r^sw(k))]
    __shared__ float Wl[64 * 128];  // 32 KB, Wl[k*128 + col]
    int tid = threadIdx.x;
    int row0 = blockIdx.x * 128;
    int c = tid & 15;   // col group: cols c*4..+3 and 64+c*4..+3
    int rg = tid >> 4;  // row group: rows rg*8..rg*8+7

    float acc[8][8] = {};
    for (int kb = 0; kb < 128; kb += 64) {
        __syncthreads();
        {   // stage W K-half (straight copy, coalesced, conflict-free)
            const float4* W4 = (const float4*)(W + (size_t)kb * 128);
            float4* Wl4 = (float4*)Wl;
            #pragma unroll
            for (int i = 0; i < 8; ++i) Wl4[tid + i * 256] = W4[tid + i * 256];
        }
        {   // stage X transposed + swizzled
            #pragma unroll
            for (int it = 0; it < 8; ++it) {
                int idx = tid + it * 256;  // 0..2047
                int r = idx >> 4;          // 0..127
                int kq = idx & 15;         // float4 index within K-half
                int gr = row0 + r;
                float4 v = (gr < n) ? ((const float4*)X)[(size_t)gr * 32 + (kb >> 2) + kq]
                                    : make_float4(0.f, 0.f, 0.f, 0.f);
                int rs = r ^ ((kq & 7) << 2);
                float* dstp = &XT[(kq * 4) * 128 + rs];
                dstp[0 * 128] = v.x;
                dstp[1 * 128] = v.y;
                dstp[2 * 128] = v.z;
                dstp[3 * 128] = v.w;
            }
        }
        __syncthreads();
        #pragma unroll 2
        for (int kk = 0; kk < 64; ++kk) {
            int sw = ((kk >> 2) & 7) << 2;
            const float* xt = &XT[kk * 128];
            float4 xa = *(const float4*)&xt[(rg * 8) ^ sw];
            float4 xb = *(const float4*)&xt[(rg * 8 + 4) ^ sw];
            const float* wr = &Wl[kk * 128];
            float4 wa = *(const float4*)&wr[c * 4];
            float4 wb = *(const float4*)&wr[64 + c * 4];
            float xv[8] = {xa.x, xa.y, xa.z, xa.w, xb.x, xb.y, xb.z, xb.w};
            float wv[8] = {wa.x, wa.y, wa.z, wa.w, wb.x, wb.y, wb.z, wb.w};
            #pragma unroll
            for (int i = 0; i < 8; ++i)
                #pragma unroll
                for (int j = 0; j < 8; ++j)
                    acc[i][j] += xv[i] * wv[j];
        }
    }

    // fused attention dots from f32 accumulators
    float4 as_a = ((const float4*)att_s)[c];
    float4 as_b = ((const float4*)att_s)[16 + c];
    float4 ad_a = ((const float4*)att_d)[c];
    float4 ad_b = ((const float4*)att_d)[16 + c];
    float asv[8] = {as_a.x, as_a.y, as_a.z, as_a.w, as_b.x, as_b.y, as_b.z, as_b.w};
    float adv[8] = {ad_a.x, ad_a.y, ad_a.z, ad_a.w, ad_b.x, ad_b.y, ad_b.z, ad_b.w};
    #pragma unroll
    for (int i = 0; i < 8; ++i) {
        float ps = 0.f, pd = 0.f;
        #pragma unroll
        for (int j = 0; j < 8; ++j) { ps += acc[i][j] * asv[j]; pd += acc[i][j] * adv[j]; }
        #pragma unroll
        for (int d = 1; d < 16; d <<= 1) { ps += __shfl_xor(ps, d); pd += __shfl_xor(pd, d); }
        int r = row0 + rg * 8 + i;
        if (c == 0 && r < n) { a_s[r] = ps; a_d[r] = pd; }
    }
    // bf16 store of XL (gather operand)
    #pragma unroll
    for (int i = 0; i < 8; ++i) {
        int r = row0 + rg * 8 + i;
        if (r < n) {
            unsigned p0 = ((unsigned)f2bf(acc[i][1]) << 16) | f2bf(acc[i][0]);
            unsigned p1 = ((unsigned)f2bf(acc[i][3]) << 16) | f2bf(acc[i][2]);
            unsigned p2 = ((unsigned)f2bf(acc[i][5]) << 16) | f2bf(acc[i][4]);
            unsigned p3 = ((unsigned)f2bf(acc[i][7]) << 16) | f2bf(acc[i][6]);
            uint2* o = (uint2*)(XLb + (size_t)r * 128);
            o[c] = make_uint2(p0, p1);       // cols c*4..c*4+3
            o[16 + c] = make_uint2(p2, p3);  // cols 64+c*4..+3
        }
    }
}

// One wave per dst node. No-max softmax (logits bounded, exp safe in f32).
// Four 16-lane groups process 4 edges/iter; each lane loads uint4 = 8 bf16
// channels (16B). Gather loop trip count is WAVE-UNIFORM with clamped shfl
// index (shfl from exec-masked lanes is undefined on CDNA). Tail (deg>64)
// has no shfl, so divergent trip counts are safe there.
__global__ __launch_bounds__(256) void k_aggregate(const unsigned short* __restrict__ xlb,
                                                   const float* __restrict__ a_s,
                                                   const float* __restrict__ a_d,
                                                   const int* __restrict__ csr_src,
                                                   const int* __restrict__ offsets,
                                                   const float* __restrict__ bias,
                                                   float* __restrict__ out, int n) {
    int wid = (blockIdx.x * blockDim.x + threadIdx.x) >> 6;
    int lane = threadIdx.x & 63;
    if (wid >= n) return;
    int beg = offsets[wid];
    int deg = offsets[wid + 1] - beg;
    float a_dn = a_d[wid];
    float w_self = __expf(lrelu(a_s[wid] + a_dn));

    int s_l = 0;
    float w_l = 0.0f;
    if (lane < deg) {
        s_l = csr_src[beg + lane];
        w_l = __expf(lrelu(a_s[s_l] + a_dn));
    }
    float zl = w_l;
    for (int j = 64 + lane; j < deg; j += 64) {
        int s = csr_src[beg + j];
        zl += __expf(lrelu(a_s[s] + a_dn));
    }
    float z = wred_sum(zl) + w_self;
    float inv = 1.0f / (z + 1e-16f);

    int qw = lane >> 4, ql = lane & 15;
    const uint4* xb4 = (const uint4*)xlb;  // row = 16 x uint4 (256B)
    float acc[8] = {};
    if (qw == 0) {  // self loop handled by group 0
        uint4 u = xb4[(size_t)wid * 16 + ql];
        bf8_fma(acc, u, w_self);
    }
    int jmax = deg < 64 ? deg : 64;
    int nt = (jmax + 3) >> 2;  // uniform trip count across the wave
    for (int t = 0; t < nt; ++t) {
        int j = (t << 2) + qw;
        int jj = j < jmax ? j : 0;  // clamped: shfl always well-defined
        float wj = __shfl(w_l, jj);
        int sj = __shfl(s_l, jj);
        if (j < jmax) {
            uint4 u = xb4[(size_t)sj * 16 + ql];
            bf8_fma(acc, u, wj);
        }
    }
    for (int j = 64 + qw; j < deg; j += 4) {  // rare tail, no shfl
        int sj = csr_src[beg + j];
        float wj = __expf(lrelu(a_s[sj] + a_dn));
        uint4 u = xb4[(size_t)sj * 16 + ql];
        bf8_fma(acc, u, wj);
    }
    #pragma unroll
    for (int k = 0; k < 8; ++k) {
        acc[k] += __shfl_xor(acc[k], 16);
        acc[k] += __shfl_xor(acc[k], 32);
    }
    if (qw == 0) {
        float4 b0 = ((const float4*)bias)[ql * 2];
        float4 b1 = ((const float4*)bias)[ql * 2 + 1];
        float4 r0, r1;
        r0.x = fmaxf(acc[0] * inv + b0.x, 0.0f);
        r0.y = fmaxf(acc[1] * inv + b0.y, 0.0f);
        r0.z = fmaxf(acc[2] * inv + b0.z, 0.0f);
        r0.w = fmaxf(acc[3] * inv + b0.w, 0.0f);
        r1.x = fmaxf(acc[4] * inv + b1.x, 0.0f);
        r1.y = fmaxf(acc[5] * inv + b1.y, 0.0f);
        r1.z = fmaxf(acc[6] * inv + b1.z, 0.0f);
        r1.w = fmaxf(acc[7] * inv + b1.w, 0.0f);
        ((float4*)out)[(size_t)wid * 32 + ql * 2] = r0;
        ((float4*)out)[(size_t)wid * 32 + ql * 2 + 1] = r1;
    }
}

extern "C" void kernel_launch(void* const* d_in, const int* in_sizes, int n_in,
                              void* d_out, int out_size, void* d_ws, size_t ws_size,
                              hipStream_t stream) {
    const float* x = (const float*)d_in[0];
    const int* edges = (const int*)d_in[1];
    const float* W1 = (const float*)d_in[2];
    const float* att_s1 = (const float*)d_in[3];
    const float* att_d1 = (const float*)d_in[4];
    const float* b1 = (const float*)d_in[5];
    const float* W2 = (const float*)d_in[6];
    const float* att_s2 = (const float*)d_in[7];
    const float* att_d2 = (const float*)d_in[8];
    const float* b2 = (const float*)d_in[9];

    const int N = in_sizes[0] / 128;
    const int E = in_sizes[1] / 2;
    const int* e_src = edges;
    const int* e_dst = edges + E;

    char* w = (char*)d_ws;
    auto carve = [&](size_t bytes) {
        char* p = w;
        w += (bytes + 255) & ~(size_t)255;
        return p;
    };
    int* counts = (int*)carve((size_t)N * 4);
    int* offsets = (int*)carve((size_t)(N + 1) * 4);
    int* rank = (int*)carve((size_t)E * 4);
    int* csr_src = (int*)carve((size_t)E * 4);
    float* a_s = (float*)carve((size_t)N * 4);
    float* a_d = (float*)carve((size_t)N * 4);
    unsigned short* xlb = (unsigned short*)carve((size_t)N * 128 * 2);
    float* h = (float*)carve((size_t)N * 128 * 4);

    float* out = (float*)d_out;

    // CSR build (shared by both layers). Vector path requires 16B-aligned
    // dst (i.e. E % 4 == 0, base alignment from harness); else scalar.
    hipMemsetAsync(counts, 0, (size_t)N * 4, stream);
    bool vec_ok = (E % 4 == 0) && ((((uintptr_t)edges) & 15) == 0);
    if (vec_ok) {
        int qb = (E / 4 + 255) / 256;
        k_hist_rank<<<qb, 256, 0, stream>>>(e_dst, E, counts, rank);
        k_scan<<<1, 1024, 0, stream>>>(counts, offsets, N);
        k_scatter<<<qb, 256, 0, stream>>>(e_src, e_dst, rank, offsets, E, csr_src);
    } else {
        int sb = (E + 255) / 256;
        k_hist_rank_s<<<sb, 256, 0, stream>>>(e_dst, E, counts, rank);
        k_scan<<<1, 1024, 0, stream>>>(counts, offsets, N);
        k_scatter_s<<<sb, 256, 0, stream>>>(e_src, e_dst, rank, offsets, E, csr_src);
    }

    int gemm_blocks = (N + 127) / 128;
    int wave_blocks = (N * 64 + 255) / 256;

    // layer 1
    k_gemm_attn<<<gemm_blocks, 256, 0, stream>>>(x, W1, att_s1, att_d1, xlb, a_s, a_d, N);
    k_aggregate<<<wave_blocks, 256, 0, stream>>>(xlb, a_s, a_d, csr_src, offsets, b1, h, N);

    // layer 2 (xlb reused; agg1 finishes before gemm2 overwrites it)
    k_gemm_attn<<<gemm_blocks, 256, 0, stream>>>(h, W2, att_s2, att_d2, xlb, a_s, a_d, N);
    k_aggregate<<<wave_blocks, 256, 0, stream>>>(xlb, a_s, a_d, csr_src, offsets, b2, out, N);
}